// Round 12
// baseline (408.848 us; speedup 1.0000x reference)
//
#include <hip/hip_runtime.h>

// Problem constants
#define S_LEN  2048
#define DMODEL 2048
#define NH     32
#define NKV    8
#define DH     64

typedef _Float16 h8   __attribute__((ext_vector_type(8)));
typedef _Float16 h4   __attribute__((ext_vector_type(4)));
typedef float    f32x4 __attribute__((ext_vector_type(4)));

// ---- async global->LDS, 16B per lane; LDS dest is wave-uniform base + lane*16
__device__ __forceinline__ void load_lds16(const _Float16* g, _Float16* l) {
  typedef const __attribute__((address_space(1))) unsigned int* gp_t;
  typedef __attribute__((address_space(3))) unsigned int* lp_t;
  __builtin_amdgcn_global_load_lds((gp_t)g, (lp_t)l, 16, 0, 0);
}

// ---- fused fp32 -> fp16 convert of all 5 inputs (dst regions adjacent in ws)
#define N8_X  2097152
#define N8_WQ 524288
#define N8_WK 131072
#define N8_WV 131072
#define N8_WO 524288
#define N8_ALL (N8_X + N8_WQ + N8_WK + N8_WV + N8_WO)
__global__ void cvt_all(const float* __restrict__ x, const float* __restrict__ wq,
                        const float* __restrict__ wk, const float* __restrict__ wv,
                        const float* __restrict__ wo, _Float16* __restrict__ dst) {
  int stride = gridDim.x * blockDim.x;
  for (int i = blockIdx.x * blockDim.x + threadIdx.x; i < N8_ALL; i += stride) {
    const float* s;
    int off;
    if (i < N8_X) { s = x; off = i; }
    else if (i < N8_X + N8_WQ) { s = wq; off = i - N8_X; }
    else if (i < N8_X + N8_WQ + N8_WK) { s = wk; off = i - (N8_X + N8_WQ); }
    else if (i < N8_X + N8_WQ + N8_WK + N8_WV) { s = wv; off = i - (N8_X + N8_WQ + N8_WK); }
    else { s = wo; off = i - (N8_X + N8_WQ + N8_WK + N8_WV); }
    float4 a = ((const float4*)s)[2 * off];
    float4 b = ((const float4*)s)[2 * off + 1];
    h8 v = {(_Float16)a.x, (_Float16)a.y, (_Float16)a.z, (_Float16)a.w,
            (_Float16)b.x, (_Float16)b.y, (_Float16)b.z, (_Float16)b.w};
    ((h8*)dst)[i] = v;
  }
}

// ---- RoPE cos/sin table, double-precision reduction (robust to fast-math trig).
__global__ void rope_table_k(float2* __restrict__ tab) {
  int i = blockIdx.x * blockDim.x + threadIdx.x;  // 2048*32 = 65536
  int s = i >> 5, d = i & 31;
  float invf = (float)exp2(-(double)d * 0.4152410118609203);  // log2(10000)/32
  float angf = (float)s * invf;  // match reference's fp32 angle
  double a = (double)angf;
  const double twopi = 6.283185307179586476925287;
  a -= floor(a / twopi) * twopi;
  tab[i] = make_float2((float)cos(a), (float)sin(a));
}

// ---- 128x128-tile GEMM, A[M][2048] f16, Bm[N][2048] f16 (B^T form), fp32 accum.
// r12: double-buffered LDS + stage(t+1)-before-compute(t) + single
// vmcnt(0)+s_barrier per K-step (T3 minimum-2-phase; the same transform that
// won +47%/+30% on attn's V/K staging). Old form exposed the full staging
// latency every K-step behind two barriers.
// MODE 1: fused Q|K|V proj (Bm = [Wq;Wk;Wv], N=3072). Per 64-col half:
//         base64 <2048: Q -> RoPE -> pre-scaled Q f16 [b][h][s][64]
//         base64 <2560: K -> RoPE -> Kh f16 [b][g][s][64] + Ko f32
//         else:         V -> Vth = V^T f16 [b][g][64][s] + Vo f32 [b][g][s][64]
// MODE 3: out proj -> yF = y [m][2048] f32
template <int MODE>
__global__ __launch_bounds__(256) void gemm128(
    const _Float16* __restrict__ A, const _Float16* __restrict__ Bm,
    _Float16* __restrict__ qH, _Float16* __restrict__ kH, float* __restrict__ kF,
    _Float16* __restrict__ vH, float* __restrict__ vF, float* __restrict__ yF,
    const float2* __restrict__ rtab, const float* __restrict__ tptr) {
  __shared__ __align__(16) _Float16 lA[2][128 * 32];
  __shared__ __align__(16) _Float16 lB[2][128 * 32];
  const int Kd = 2048;
  int t = threadIdx.x;
  int w = t >> 6, lane = t & 63;
  int n0 = blockIdx.x * 128, m0 = blockIdx.y * 128;
  int wr = w >> 1, wc = w & 1;
  int lq = lane & 15, hi = lane >> 4;

  const _Float16* gA = A + (size_t)(m0 + w * 32 + (lane >> 2)) * Kd + (lane & 3) * 8;
  const _Float16* gB = Bm + (size_t)(n0 + w * 32 + (lane >> 2)) * Kd + (lane & 3) * 8;
  int dOff0 = (w * 32) * 32;        // wave's stage dest rows [w*32, w*32+16)
  int dOff1 = (w * 32 + 16) * 32;   // rows [w*32+16, w*32+32)

  f32x4 z4 = {0.f, 0.f, 0.f, 0.f};
  f32x4 acc[4][4];
#pragma unroll
  for (int i = 0; i < 4; i++)
#pragma unroll
    for (int j = 0; j < 4; j++) acc[i][j] = z4;

  // prologue: stage K-step 0 into buffer 0
  load_lds16(gA, &lA[0][dOff0]);
  load_lds16(gA + (size_t)16 * Kd, &lA[0][dOff1]);
  load_lds16(gB, &lB[0][dOff0]);
  load_lds16(gB + (size_t)16 * Kd, &lB[0][dOff1]);
  asm volatile("s_waitcnt vmcnt(0)" ::: "memory");
  __builtin_amdgcn_s_barrier();

  for (int k0 = 0; k0 < Kd; k0 += 32) {
    int cur = (k0 >> 5) & 1;
    // issue stage of K-step t+1 into the other buffer; lands during this
    // step's ds_read+MFMA phase, drained by the end-of-step vmcnt(0).
    if (k0 + 32 < Kd) {
      int nxt = cur ^ 1;
      load_lds16(gA + k0 + 32, &lA[nxt][dOff0]);
      load_lds16(gA + (size_t)16 * Kd + k0 + 32, &lA[nxt][dOff1]);
      load_lds16(gB + k0 + 32, &lB[nxt][dOff0]);
      load_lds16(gB + (size_t)16 * Kd + k0 + 32, &lB[nxt][dOff1]);
    }
    h8 af[4], bf[4];
#pragma unroll
    for (int i = 0; i < 4; i++)
      af[i] = *(const h8*)&lA[cur][(wr * 64 + i * 16 + lq) * 32 + hi * 8];
#pragma unroll
    for (int j = 0; j < 4; j++)
      bf[j] = *(const h8*)&lB[cur][(wc * 64 + j * 16 + lq) * 32 + hi * 8];
#pragma unroll
    for (int i = 0; i < 4; i++)
#pragma unroll
      for (int j = 0; j < 4; j++)
        acc[i][j] = __builtin_amdgcn_mfma_f32_16x16x32_f16(af[i], bf[j], acc[i][j], 0, 0, 0);
    // next-step stage landed; all waves' reads of buf[cur] complete (their
    // MFMAs consumed them) -> barrier, then buf[cur] may be overwritten.
    asm volatile("s_waitcnt vmcnt(0)" ::: "memory");
    __builtin_amdgcn_s_barrier();
  }

  if (MODE == 3) {
#pragma unroll
    for (int ci = 0; ci < 4; ci++) {
      int col = n0 + wc * 64 + ci * 16 + lq;
#pragma unroll
      for (int ri = 0; ri < 4; ri++)
#pragma unroll
        for (int r = 0; r < 4; r++) {
          int m = m0 + wr * 64 + ri * 16 + hi * 4 + r;
          yF[(size_t)m * DMODEL + col] = acc[ri][ci][r];
        }
    }
  } else {  // MODE 1: fused Q|K|V (each 64-col half is purely one head of one output)
    int base64 = n0 + wc * 64;
    if (base64 < 2048) {
      // Q: RoPE + fold softmax scale (incl. log2e for exp2-domain attention)
      float qsc = 0.125f / fmaxf(fabsf(tptr[0]), 1e-6f) * 1.4426950408889634f;
      int head = base64 >> 6;
#pragma unroll
      for (int ci = 0; ci < 2; ci++) {
        int dlo = ci * 16 + lq;
#pragma unroll
        for (int ri = 0; ri < 4; ri++)
#pragma unroll
          for (int r = 0; r < 4; r++) {
            int m = m0 + wr * 64 + ri * 16 + hi * 4 + r;
            int b = m >> 11, s = m & 2047;
            float2 cs = rtab[s * 32 + dlo];
            float lo = acc[ri][ci][r], hv = acc[ri][ci + 2][r];
            float olo = (lo * cs.x - hv * cs.y) * qsc;
            float ohi = (hv * cs.x + lo * cs.y) * qsc;
            size_t base = ((size_t)(b * NH + head) * S_LEN + s) * DH;
            qH[base + dlo] = (_Float16)olo;
            qH[base + dlo + 32] = (_Float16)ohi;
          }
      }
    } else if (base64 < 2560) {
      int head = (base64 - 2048) >> 6;
#pragma unroll
      for (int ci = 0; ci < 2; ci++) {
        int dlo = ci * 16 + lq;
#pragma unroll
        for (int ri = 0; ri < 4; ri++)
#pragma unroll
          for (int r = 0; r < 4; r++) {
            int m = m0 + wr * 64 + ri * 16 + hi * 4 + r;
            int b = m >> 11, s = m & 2047;
            float2 cs = rtab[s * 32 + dlo];
            float lo = acc[ri][ci][r], hv = acc[ri][ci + 2][r];
            float olo = lo * cs.x - hv * cs.y;
            float ohi = hv * cs.x + lo * cs.y;
            size_t bb = ((size_t)(b * NKV + head) * S_LEN + s) * DH;
            kH[bb + dlo] = (_Float16)olo;
            kH[bb + dlo + 32] = (_Float16)ohi;
            kF[bb + dlo] = olo;
            kF[bb + dlo + 32] = ohi;
          }
      }
    } else {
      int head = (base64 - 2560) >> 6;
#pragma unroll
      for (int ci = 0; ci < 4; ci++) {
        int d = ci * 16 + lq;
#pragma unroll
        for (int ri = 0; ri < 4; ri++)
#pragma unroll
          for (int r = 0; r < 4; r++) {
            int m = m0 + wr * 64 + ri * 16 + hi * 4 + r;
            int b = m >> 11, s = m & 2047;
            float v = acc[ri][ci][r];
            vH[((size_t)(b * NKV + head) * DH + d) * S_LEN + s] = (_Float16)v;  // V^T
            vF[((size_t)(b * NKV + head) * S_LEN + s) * DH + d] = v;            // V fp32
          }
      }
    }
  }
}

// ---- causal GQA flash attention. (r11 structure, FROZEN this round)
// Grid (8,256): xcd=bx pins 16 (b,h) per XCD; chunk = 15-(by>>4) -> longest
// first. Block = 4 waves, wave w owns 32 q-rows. launch_bounds (256,3): the
// ONLY no-spill budget (3x confirmed). K and V staged into block-shared
// double-buffered swizzled LDS via global_load_lds; one vmcnt(0)+s_barrier
// per tile; stage(t+1) issued right after. Swizzle (both-sides, rule #21):
// physical 16B block pb at row r holds logical block pb^(r&7).
__global__ __launch_bounds__(256, 3) void attn_fwd(
    const _Float16* __restrict__ Q, const _Float16* __restrict__ K,
    const _Float16* __restrict__ Vt, _Float16* __restrict__ AO) {
  __shared__ __align__(16) _Float16 lP[4][32 * 72];  // per-wave P[q32][kv64], stride 72
  __shared__ __align__(16) _Float16 lK[2][64 * 64];  // shared K tile, dbuf, swizzled
  __shared__ __align__(16) _Float16 lV[2][64 * 64];  // shared V^T tile, dbuf, swizzled
  int t = threadIdx.x, w = t >> 6, lane = t & 63;
  int lq = lane & 15, hi = lane >> 4;

  int bh = blockIdx.x * 16 + (blockIdx.y & 15);  // 16 consecutive (b,h) per XCD
  int qb = 15 - (blockIdx.y >> 4);               // descending chunk order
  int b = bh >> 5, h = bh & 31, g = h >> 2;

  const _Float16* Qp = Q + ((size_t)(b * NH + h) * S_LEN) * DH;
  const _Float16* Kp = K + ((size_t)(b * NKV + g) * S_LEN) * DH;
  const _Float16* Vp = Vt + ((size_t)(b * NKV + g) * DH) * S_LEN;

  f32x4 z4 = {0.f, 0.f, 0.f, 0.f};
  int q0 = qb * 128 + w * 32;

  // staging addresses: wave w covers rows [w*16, w*16+16) of the 64-row tile,
  // lane l -> row +(l>>3), physical block l&7 <- logical block (l&7)^(l>>3).
  int swz = ((lane & 7) ^ (lane >> 3)) * 8;
  size_t sko0 = (size_t)(w * 16 + (lane >> 3)) * DH + (size_t)swz;      // K (row stride 64)
  size_t svo0 = (size_t)(w * 16 + (lane >> 3)) * S_LEN + (size_t)swz;   // V^T (row stride 2048)

  // Q fragments in registers (B-operand of QK^T), pre-scaled
  h8 qf[2][2];
#pragma unroll
  for (int cf = 0; cf < 2; cf++)
#pragma unroll
    for (int dc = 0; dc < 2; dc++)
      qf[cf][dc] = *(const h8*)&Qp[(size_t)(q0 + lq + 16 * cf) * DH + dc * 32 + hi * 8];

  f32x4 ot[4][2];  // O^T: [dv 4x16][q 2x16]
#pragma unroll
  for (int rf = 0; rf < 4; rf++)
#pragma unroll
    for (int cf = 0; cf < 2; cf++) ot[rf][cf] = z4;
  float mrun[2] = {-3e38f, -3e38f};
  float lrun[2] = {0.f, 0.f};

  int NT = 2 * qb + 2;  // uniform tile count for all waves (barrier lockstep)

  // prologue: stage K(0), V(0) into buffer 0
  load_lds16(Kp + sko0, &lK[0][(w * 16) * 64]);
  load_lds16(Kp + sko0 + (size_t)8 * DH, &lK[0][(w * 16 + 8) * 64]);
  load_lds16(Vp + svo0, &lV[0][(w * 16) * 64]);
  load_lds16(Vp + svo0 + (size_t)8 * S_LEN, &lV[0][(w * 16 + 8) * 64]);

  for (int tk = 0; tk < NT; tk++) {
    int kv0 = tk * 64;

    // staged K(tk)/V(tk) landed (own-wave vmem drain) + block-wide sync
    asm volatile("s_waitcnt vmcnt(0)" ::: "memory");
    __builtin_amdgcn_s_barrier();

    // issue stage of K(tk+1)/V(tk+1) into the other buffer (its previous
    // readers finished before this barrier). Lands during this whole tile;
    // drained by next loop-top vmcnt(0). Block-uniform guard.
    if (tk + 1 < NT) {
      _Float16* nK = &lK[(tk + 1) & 1][0];
      _Float16* nV = &lV[(tk + 1) & 1][0];
      size_t kvn = (size_t)(kv0 + 64);
      load_lds16(Kp + kvn * DH + sko0, nK + (w * 16) * 64);
      load_lds16(Kp + kvn * DH + sko0 + (size_t)8 * DH, nK + (w * 16 + 8) * 64);
      load_lds16(Vp + svo0 + kvn, nV + (w * 16) * 64);
      load_lds16(Vp + svo0 + kvn + (size_t)8 * S_LEN, nV + (w * 16 + 8) * 64);
    }

    // S^T = K Q^T (contraction over d); K from shared swizzled LDS.
    f32x4 sc[4][2];
#pragma unroll
    for (int rf = 0; rf < 4; rf++)
#pragma unroll
      for (int cf = 0; cf < 2; cf++) sc[rf][cf] = z4;
    {
      const _Float16* kb = &lK[tk & 1][0];
#pragma unroll
      for (int dc = 0; dc < 2; dc++) {
        h8 kf[4];
#pragma unroll
        for (int rf = 0; rf < 4; rf++)
          kf[rf] = *(const h8*)&kb[(rf * 16 + lq) * 64 + (((dc * 4 + hi) ^ (lq & 7)) * 8)];
#pragma unroll
        for (int rf = 0; rf < 4; rf++)
#pragma unroll
          for (int cf = 0; cf < 2; cf++)
            sc[rf][cf] = __builtin_amdgcn_mfma_f32_16x16x32_f16(kf[rf], qf[cf][dc], sc[rf][cf], 0, 0, 0);
      }
    }

    // causal mask (diag tiles only; no scale pass needed)
    if (kv0 + 63 > q0) {
#pragma unroll
      for (int rf = 0; rf < 4; rf++)
#pragma unroll
        for (int cf = 0; cf < 2; cf++)
#pragma unroll
          for (int r = 0; r < 4; r++) {
            int kv = kv0 + rf * 16 + hi * 4 + r;
            int q = q0 + lq + 16 * cf;
            if (kv > q) sc[rf][cf][r] = -1e30f;
          }
    }

    // row max (per q): 16 in-lane + 2 shuffles
    float mt[2];
#pragma unroll
    for (int cf = 0; cf < 2; cf++) {
      float m2 = -3e38f;
#pragma unroll
      for (int rf = 0; rf < 4; rf++)
#pragma unroll
        for (int r = 0; r < 4; r++) m2 = fmaxf(m2, sc[rf][cf][r]);
      m2 = fmaxf(m2, __shfl_xor(m2, 16));
      m2 = fmaxf(m2, __shfl_xor(m2, 32));
      mt[cf] = m2;
    }

    // defer-max (T13): only rescale when the max moved by > 8 (log2 units)
    bool need = !__all((mt[0] - mrun[0] <= 8.f) && (mt[1] - mrun[1] <= 8.f));
    if (need) {
#pragma unroll
      for (int cf = 0; cf < 2; cf++) {
        float mnew = fmaxf(mrun[cf], mt[cf]);
        float al = __builtin_amdgcn_exp2f(mrun[cf] - mnew);
        mrun[cf] = mnew;
        lrun[cf] *= al;
#pragma unroll
        for (int rf = 0; rf < 4; rf++)
#pragma unroll
          for (int r = 0; r < 4; r++) ot[rf][cf][r] *= al;
      }
    }

    // P = exp2(S - m), row sums
    float ls[2] = {0.f, 0.f};
#pragma unroll
    for (int rf = 0; rf < 4; rf++)
#pragma unroll
      for (int cf = 0; cf < 2; cf++)
#pragma unroll
        for (int r = 0; r < 4; r++) {
          float p = __builtin_amdgcn_exp2f(sc[rf][cf][r] - mrun[cf]);
          sc[rf][cf][r] = p;
          ls[cf] += p;
        }
#pragma unroll
    for (int cf = 0; cf < 2; cf++) {
      float s2 = ls[cf];
      s2 += __shfl_xor(s2, 16);
      s2 += __shfl_xor(s2, 32);
      lrun[cf] += s2;
    }

    // pack P -> wave-private LDS [q][kv]
#pragma unroll
    for (int rf = 0; rf < 4; rf++)
#pragma unroll
      for (int cf = 0; cf < 2; cf++) {
        h4 p4;
#pragma unroll
        for (int r = 0; r < 4; r++) p4[r] = (_Float16)sc[rf][cf][r];
        *(h4*)&lP[w][(lq + 16 * cf) * 72 + rf * 16 + hi * 4] = p4;
      }
    asm volatile("s_waitcnt lgkmcnt(0)" ::: "memory");
    __builtin_amdgcn_sched_barrier(0);

    // O^T += V^T P^T (contraction over kv). V from shared swizzled LDS.
    {
      const _Float16* vb = &lV[tk & 1][0];
#pragma unroll
      for (int kvc = 0; kvc < 2; kvc++) {
        h8 vf[4];
#pragma unroll
        for (int rf = 0; rf < 4; rf++)
          vf[rf] = *(const h8*)&vb[(rf * 16 + lq) * 64 + (((kvc * 4 + hi) ^ (lq & 7)) * 8)];
        h8 pb[2];
#pragma unroll
        for (int cf = 0; cf < 2; cf++)
          pb[cf] = *(const h8*)&lP[w][(lq + 16 * cf) * 72 + kvc * 32 + hi * 8];
#pragma unroll
        for (int rf = 0; rf < 4; rf++)
#pragma unroll
          for (int cf = 0; cf < 2; cf++)
            ot[rf][cf] = __builtin_amdgcn_mfma_f32_16x16x32_f16(vf[rf], pb[cf], ot[rf][cf], 0, 0, 0);
      }
    }
    // no end-of-tile barrier: ds_read data already consumed by MFMAs above;
    // next loop-top vmcnt(0)+s_barrier orders buffer reuse.
  }

  // normalize + store to AO[b*S+q][h*64+dv] f16 (input of out-proj GEMM)
#pragma unroll
  for (int cf = 0; cf < 2; cf++) {
    float inv = 1.0f / lrun[cf];
    size_t row = (size_t)b * S_LEN + q0 + lq + 16 * cf;
#pragma unroll
    for (int rf = 0; rf < 4; rf++) {
      h4 o;
#pragma unroll
      for (int r = 0; r < 4; r++) o[r] = (_Float16)(ot[rf][cf][r] * inv);
      *(h4*)&AO[row * DMODEL + h * DH + rf * 16 + hi * 4] = o;
    }
  }
}

extern "C" void kernel_launch(void* const* d_in, const int* in_sizes, int n_in,
                              void* d_out, int out_size, void* d_ws, size_t ws_size,
                              hipStream_t stream) {
  const float* x  = (const float*)d_in[0];
  const float* Wq = (const float*)d_in[1];
  const float* Wk = (const float*)d_in[2];
  const float* Wv = (const float*)d_in[3];
  const float* Wo = (const float*)d_in[4];
  const float* tp = (const float*)d_in[5];

  float* y  = (float*)d_out;                 // 16,777,216 f32
  float* Ko = y + (size_t)16777216;          //  4,194,304 (post-RoPE K fp32)
  float* Vo = Ko + (size_t)4194304;          //  4,194,304 (V fp32)

  // workspace carve (fp16 elems) — total 68.5 MB. xh..woh adjacent => single cvt;
  // wqh/wkh/wvh adjacent => ONE fused QKV GEMM (N=3072; 2048/2560 are 128-aligned).
  _Float16* xh  = (_Float16*)d_ws;           // 16,777,216
  _Float16* wqh = xh + 16777216;             //  4,194,304
  _Float16* wkh = wqh + 4194304;             //  1,048,576
  _Float16* wvh = wkh + 1048576;             //  1,048,576
  _Float16* woh = wvh + 1048576;             //  4,194,304
  _Float16* Kh  = woh + 4194304;             //  4,194,304  [b][g][s][64]
  _Float16* Vth = Kh + 4194304;              //  4,194,304  [b][g][64][s]
  float2*   rtab = (float2*)(Vth + 4194304); //    524,288 B
  _Float16* AOh = xh;                        // alias: x dead after QKV GEMM
  _Float16* Qh  = (_Float16*)d_out;          // alias: first 32MB of y; y written last
  (void)wkh; (void)wvh;

  cvt_all<<<2048, 256, 0, stream>>>(x, Wq, Wk, Wv, Wo, xh);
  rope_table_k<<<256, 256, 0, stream>>>(rtab);

  gemm128<1><<<dim3(24, 64), 256, 0, stream>>>(xh, wqh, Qh, Kh, Ko, Vth, Vo, nullptr, rtab, tp);
  attn_fwd<<<dim3(8, 256), 256, 0, stream>>>(Qh, Kh, Vth, AOh);
  gemm128<3><<<dim3(16, 64), 256, 0, stream>>>(AOh, woh, nullptr, nullptr, nullptr, nullptr, nullptr, y, rtab, tp);
}

// Round 13
// 396.720 us; speedup vs baseline: 1.0306x; 1.0306x over previous
//
#include <hip/hip_runtime.h>

// Problem constants
#define S_LEN  2048
#define DMODEL 2048
#define NH     32
#define NKV    8
#define DH     64

typedef _Float16 h8   __attribute__((ext_vector_type(8)));
typedef _Float16 h4   __attribute__((ext_vector_type(4)));
typedef float    f32x4 __attribute__((ext_vector_type(4)));

// ---- async global->LDS, 16B per lane; LDS dest is wave-uniform base + lane*16
__device__ __forceinline__ void load_lds16(const _Float16* g, _Float16* l) {
  typedef const __attribute__((address_space(1))) unsigned int* gp_t;
  typedef __attribute__((address_space(3))) unsigned int* lp_t;
  __builtin_amdgcn_global_load_lds((gp_t)g, (lp_t)l, 16, 0, 0);
}

// ---- fused fp32 -> fp16 convert of all 5 inputs (dst regions adjacent in ws)
#define N8_X  2097152
#define N8_WQ 524288
#define N8_WK 131072
#define N8_WV 131072
#define N8_WO 524288
#define N8_ALL (N8_X + N8_WQ + N8_WK + N8_WV + N8_WO)
__global__ void cvt_all(const float* __restrict__ x, const float* __restrict__ wq,
                        const float* __restrict__ wk, const float* __restrict__ wv,
                        const float* __restrict__ wo, _Float16* __restrict__ dst) {
  int stride = gridDim.x * blockDim.x;
  for (int i = blockIdx.x * blockDim.x + threadIdx.x; i < N8_ALL; i += stride) {
    const float* s;
    int off;
    if (i < N8_X) { s = x; off = i; }
    else if (i < N8_X + N8_WQ) { s = wq; off = i - N8_X; }
    else if (i < N8_X + N8_WQ + N8_WK) { s = wk; off = i - (N8_X + N8_WQ); }
    else if (i < N8_X + N8_WQ + N8_WK + N8_WV) { s = wv; off = i - (N8_X + N8_WQ + N8_WK); }
    else { s = wo; off = i - (N8_X + N8_WQ + N8_WK + N8_WV); }
    float4 a = ((const float4*)s)[2 * off];
    float4 b = ((const float4*)s)[2 * off + 1];
    h8 v = {(_Float16)a.x, (_Float16)a.y, (_Float16)a.z, (_Float16)a.w,
            (_Float16)b.x, (_Float16)b.y, (_Float16)b.z, (_Float16)b.w};
    ((h8*)dst)[i] = v;
  }
}

// ---- RoPE cos/sin table, double-precision reduction (robust to fast-math trig).
__global__ void rope_table_k(float2* __restrict__ tab) {
  int i = blockIdx.x * blockDim.x + threadIdx.x;  // 2048*32 = 65536
  int s = i >> 5, d = i & 31;
  float invf = (float)exp2(-(double)d * 0.4152410118609203);  // log2(10000)/32
  float angf = (float)s * invf;  // match reference's fp32 angle
  double a = (double)angf;
  const double twopi = 6.283185307179586476925287;
  a -= floor(a / twopi) * twopi;
  tab[i] = make_float2((float)cos(a), (float)sin(a));
}

// ---- 128x128-tile GEMM, A[M][2048] f16, Bm[N][2048] f16 (B^T form), fp32 accum.
// r13: 512-thread / 8-wave blocks (wave grid 4x2, per-wave 32x64 output,
// acc[2][4] = 32 AGPR vs the old 4-wave acc[4][4]=64). Unified regs ~half ->
// 4 waves/SIMD (was 2): the r12 counters showed the GEMM was occupancy-
// starved (184 unified regs -> 22% occupancy), not barrier-bound (dbuf was
// neutral). Staging: 1 global_load_lds per matrix per thread (wave covers
// 16 rows, dest = wave base + lane*16). Keep the r12 dbuf schedule.
// MODE 1: fused Q|K|V proj (Bm = [Wq;Wk;Wv], N=3072). Per 64-col half:
//         base64 <2048: Q -> RoPE -> pre-scaled Q f16 [b][h][s][64]
//         base64 <2560: K -> RoPE -> Kh f16 [b][g][s][64] + Ko f32
//         else:         V -> Vth = V^T f16 [b][g][64][s] + Vo f32 [b][g][s][64]
// MODE 3: out proj -> yF = y [m][2048] f32
template <int MODE>
__global__ __launch_bounds__(512) void gemm128(
    const _Float16* __restrict__ A, const _Float16* __restrict__ Bm,
    _Float16* __restrict__ qH, _Float16* __restrict__ kH, float* __restrict__ kF,
    _Float16* __restrict__ vH, float* __restrict__ vF, float* __restrict__ yF,
    const float2* __restrict__ rtab, const float* __restrict__ tptr) {
  __shared__ __align__(16) _Float16 lA[2][128 * 32];
  __shared__ __align__(16) _Float16 lB[2][128 * 32];
  const int Kd = 2048;
  int t = threadIdx.x;
  int w = t >> 6, lane = t & 63;
  int n0 = blockIdx.x * 128, m0 = blockIdx.y * 128;
  int wr = w >> 1, wc = w & 1;        // 4x2 wave grid: rows wr*32, cols wc*64
  int lq = lane & 15, hi = lane >> 4;

  // staging: wave w covers rows [w*16, w*16+16); lane l -> row +(l>>2), 16B block l&3
  const _Float16* gA = A + (size_t)(m0 + w * 16 + (lane >> 2)) * Kd + (lane & 3) * 8;
  const _Float16* gB = Bm + (size_t)(n0 + w * 16 + (lane >> 2)) * Kd + (lane & 3) * 8;
  int dOff = (w * 16) * 32;  // wave's LDS dest (f16 elems)

  f32x4 z4 = {0.f, 0.f, 0.f, 0.f};
  f32x4 acc[2][4];
#pragma unroll
  for (int i = 0; i < 2; i++)
#pragma unroll
    for (int j = 0; j < 4; j++) acc[i][j] = z4;

  // prologue: stage K-step 0 into buffer 0
  load_lds16(gA, &lA[0][dOff]);
  load_lds16(gB, &lB[0][dOff]);
  asm volatile("s_waitcnt vmcnt(0)" ::: "memory");
  __builtin_amdgcn_s_barrier();

  for (int k0 = 0; k0 < Kd; k0 += 32) {
    int cur = (k0 >> 5) & 1;
    // issue stage of K-step t+1 into the other buffer (lands during compute)
    if (k0 + 32 < Kd) {
      load_lds16(gA + k0 + 32, &lA[cur ^ 1][dOff]);
      load_lds16(gB + k0 + 32, &lB[cur ^ 1][dOff]);
    }
    h8 af[2], bf[4];
#pragma unroll
    for (int i = 0; i < 2; i++)
      af[i] = *(const h8*)&lA[cur][(wr * 32 + i * 16 + lq) * 32 + hi * 8];
#pragma unroll
    for (int j = 0; j < 4; j++)
      bf[j] = *(const h8*)&lB[cur][(wc * 64 + j * 16 + lq) * 32 + hi * 8];
#pragma unroll
    for (int i = 0; i < 2; i++)
#pragma unroll
      for (int j = 0; j < 4; j++)
        acc[i][j] = __builtin_amdgcn_mfma_f32_16x16x32_f16(af[i], bf[j], acc[i][j], 0, 0, 0);
    // next-step stage landed + all waves consumed buf[cur] -> may overwrite
    asm volatile("s_waitcnt vmcnt(0)" ::: "memory");
    __builtin_amdgcn_s_barrier();
  }

  if (MODE == 3) {
#pragma unroll
    for (int ci = 0; ci < 4; ci++) {
      int col = n0 + wc * 64 + ci * 16 + lq;
#pragma unroll
      for (int mi = 0; mi < 2; mi++)
#pragma unroll
        for (int r = 0; r < 4; r++) {
          int m = m0 + wr * 32 + mi * 16 + hi * 4 + r;
          yF[(size_t)m * DMODEL + col] = acc[mi][ci][r];
        }
    }
  } else {  // MODE 1: fused Q|K|V (each 64-col wave half is one head of one output)
    int base64 = n0 + wc * 64;
    if (base64 < 2048) {
      // Q: RoPE + fold softmax scale (incl. log2e for exp2-domain attention)
      float qsc = 0.125f / fmaxf(fabsf(tptr[0]), 1e-6f) * 1.4426950408889634f;
      int head = base64 >> 6;
#pragma unroll
      for (int ci = 0; ci < 2; ci++) {
        int dlo = ci * 16 + lq;
#pragma unroll
        for (int mi = 0; mi < 2; mi++)
#pragma unroll
          for (int r = 0; r < 4; r++) {
            int m = m0 + wr * 32 + mi * 16 + hi * 4 + r;
            int b = m >> 11, s = m & 2047;
            float2 cs = rtab[s * 32 + dlo];
            float lo = acc[mi][ci][r], hv = acc[mi][ci + 2][r];
            float olo = (lo * cs.x - hv * cs.y) * qsc;
            float ohi = (hv * cs.x + lo * cs.y) * qsc;
            size_t base = ((size_t)(b * NH + head) * S_LEN + s) * DH;
            qH[base + dlo] = (_Float16)olo;
            qH[base + dlo + 32] = (_Float16)ohi;
          }
      }
    } else if (base64 < 2560) {
      int head = (base64 - 2048) >> 6;
#pragma unroll
      for (int ci = 0; ci < 2; ci++) {
        int dlo = ci * 16 + lq;
#pragma unroll
        for (int mi = 0; mi < 2; mi++)
#pragma unroll
          for (int r = 0; r < 4; r++) {
            int m = m0 + wr * 32 + mi * 16 + hi * 4 + r;
            int b = m >> 11, s = m & 2047;
            float2 cs = rtab[s * 32 + dlo];
            float lo = acc[mi][ci][r], hv = acc[mi][ci + 2][r];
            float olo = lo * cs.x - hv * cs.y;
            float ohi = hv * cs.x + lo * cs.y;
            size_t bb = ((size_t)(b * NKV + head) * S_LEN + s) * DH;
            kH[bb + dlo] = (_Float16)olo;
            kH[bb + dlo + 32] = (_Float16)ohi;
            kF[bb + dlo] = olo;
            kF[bb + dlo + 32] = ohi;
          }
      }
    } else {
      int head = (base64 - 2560) >> 6;
#pragma unroll
      for (int ci = 0; ci < 4; ci++) {
        int d = ci * 16 + lq;
#pragma unroll
        for (int mi = 0; mi < 2; mi++)
#pragma unroll
          for (int r = 0; r < 4; r++) {
            int m = m0 + wr * 32 + mi * 16 + hi * 4 + r;
            int b = m >> 11, s = m & 2047;
            float v = acc[mi][ci][r];
            vH[((size_t)(b * NKV + head) * DH + d) * S_LEN + s] = (_Float16)v;  // V^T
            vF[((size_t)(b * NKV + head) * S_LEN + s) * DH + d] = v;            // V fp32
          }
      }
    }
  }
}

// ---- causal GQA flash attention. (r11/r12 structure, FROZEN)
// Grid (8,256): xcd=bx pins 16 (b,h) per XCD; chunk = 15-(by>>4) -> longest
// first. Block = 4 waves, wave w owns 32 q-rows. launch_bounds (256,3): the
// ONLY no-spill budget (3x confirmed). K and V staged into block-shared
// double-buffered swizzled LDS via global_load_lds; one vmcnt(0)+s_barrier
// per tile; stage(t+1) issued right after. Swizzle (both-sides, rule #21):
// physical 16B block pb at row r holds logical block pb^(r&7).
__global__ __launch_bounds__(256, 3) void attn_fwd(
    const _Float16* __restrict__ Q, const _Float16* __restrict__ K,
    const _Float16* __restrict__ Vt, _Float16* __restrict__ AO) {
  __shared__ __align__(16) _Float16 lP[4][32 * 72];  // per-wave P[q32][kv64], stride 72
  __shared__ __align__(16) _Float16 lK[2][64 * 64];  // shared K tile, dbuf, swizzled
  __shared__ __align__(16) _Float16 lV[2][64 * 64];  // shared V^T tile, dbuf, swizzled
  int t = threadIdx.x, w = t >> 6, lane = t & 63;
  int lq = lane & 15, hi = lane >> 4;

  int bh = blockIdx.x * 16 + (blockIdx.y & 15);  // 16 consecutive (b,h) per XCD
  int qb = 15 - (blockIdx.y >> 4);               // descending chunk order
  int b = bh >> 5, h = bh & 31, g = h >> 2;

  const _Float16* Qp = Q + ((size_t)(b * NH + h) * S_LEN) * DH;
  const _Float16* Kp = K + ((size_t)(b * NKV + g) * S_LEN) * DH;
  const _Float16* Vp = Vt + ((size_t)(b * NKV + g) * DH) * S_LEN;

  f32x4 z4 = {0.f, 0.f, 0.f, 0.f};
  int q0 = qb * 128 + w * 32;

  // staging addresses: wave w covers rows [w*16, w*16+16) of the 64-row tile,
  // lane l -> row +(l>>3), physical block l&7 <- logical block (l&7)^(l>>3).
  int swz = ((lane & 7) ^ (lane >> 3)) * 8;
  size_t sko0 = (size_t)(w * 16 + (lane >> 3)) * DH + (size_t)swz;      // K (row stride 64)
  size_t svo0 = (size_t)(w * 16 + (lane >> 3)) * S_LEN + (size_t)swz;   // V^T (row stride 2048)

  // Q fragments in registers (B-operand of QK^T), pre-scaled
  h8 qf[2][2];
#pragma unroll
  for (int cf = 0; cf < 2; cf++)
#pragma unroll
    for (int dc = 0; dc < 2; dc++)
      qf[cf][dc] = *(const h8*)&Qp[(size_t)(q0 + lq + 16 * cf) * DH + dc * 32 + hi * 8];

  f32x4 ot[4][2];  // O^T: [dv 4x16][q 2x16]
#pragma unroll
  for (int rf = 0; rf < 4; rf++)
#pragma unroll
    for (int cf = 0; cf < 2; cf++) ot[rf][cf] = z4;
  float mrun[2] = {-3e38f, -3e38f};
  float lrun[2] = {0.f, 0.f};

  int NT = 2 * qb + 2;  // uniform tile count for all waves (barrier lockstep)

  // prologue: stage K(0), V(0) into buffer 0
  load_lds16(Kp + sko0, &lK[0][(w * 16) * 64]);
  load_lds16(Kp + sko0 + (size_t)8 * DH, &lK[0][(w * 16 + 8) * 64]);
  load_lds16(Vp + svo0, &lV[0][(w * 16) * 64]);
  load_lds16(Vp + svo0 + (size_t)8 * S_LEN, &lV[0][(w * 16 + 8) * 64]);

  for (int tk = 0; tk < NT; tk++) {
    int kv0 = tk * 64;

    // staged K(tk)/V(tk) landed (own-wave vmem drain) + block-wide sync
    asm volatile("s_waitcnt vmcnt(0)" ::: "memory");
    __builtin_amdgcn_s_barrier();

    // issue stage of K(tk+1)/V(tk+1) into the other buffer (its previous
    // readers finished before this barrier). Lands during this whole tile;
    // drained by next loop-top vmcnt(0). Block-uniform guard.
    if (tk + 1 < NT) {
      _Float16* nK = &lK[(tk + 1) & 1][0];
      _Float16* nV = &lV[(tk + 1) & 1][0];
      size_t kvn = (size_t)(kv0 + 64);
      load_lds16(Kp + kvn * DH + sko0, nK + (w * 16) * 64);
      load_lds16(Kp + kvn * DH + sko0 + (size_t)8 * DH, nK + (w * 16 + 8) * 64);
      load_lds16(Vp + svo0 + kvn, nV + (w * 16) * 64);
      load_lds16(Vp + svo0 + kvn + (size_t)8 * S_LEN, nV + (w * 16 + 8) * 64);
    }

    // S^T = K Q^T (contraction over d); K from shared swizzled LDS.
    f32x4 sc[4][2];
#pragma unroll
    for (int rf = 0; rf < 4; rf++)
#pragma unroll
      for (int cf = 0; cf < 2; cf++) sc[rf][cf] = z4;
    {
      const _Float16* kb = &lK[tk & 1][0];
#pragma unroll
      for (int dc = 0; dc < 2; dc++) {
        h8 kf[4];
#pragma unroll
        for (int rf = 0; rf < 4; rf++)
          kf[rf] = *(const h8*)&kb[(rf * 16 + lq) * 64 + (((dc * 4 + hi) ^ (lq & 7)) * 8)];
#pragma unroll
        for (int rf = 0; rf < 4; rf++)
#pragma unroll
          for (int cf = 0; cf < 2; cf++)
            sc[rf][cf] = __builtin_amdgcn_mfma_f32_16x16x32_f16(kf[rf], qf[cf][dc], sc[rf][cf], 0, 0, 0);
      }
    }

    // causal mask (diag tiles only; no scale pass needed)
    if (kv0 + 63 > q0) {
#pragma unroll
      for (int rf = 0; rf < 4; rf++)
#pragma unroll
        for (int cf = 0; cf < 2; cf++)
#pragma unroll
          for (int r = 0; r < 4; r++) {
            int kv = kv0 + rf * 16 + hi * 4 + r;
            int q = q0 + lq + 16 * cf;
            if (kv > q) sc[rf][cf][r] = -1e30f;
          }
    }

    // row max (per q): 16 in-lane + 2 shuffles
    float mt[2];
#pragma unroll
    for (int cf = 0; cf < 2; cf++) {
      float m2 = -3e38f;
#pragma unroll
      for (int rf = 0; rf < 4; rf++)
#pragma unroll
        for (int r = 0; r < 4; r++) m2 = fmaxf(m2, sc[rf][cf][r]);
      m2 = fmaxf(m2, __shfl_xor(m2, 16));
      m2 = fmaxf(m2, __shfl_xor(m2, 32));
      mt[cf] = m2;
    }

    // defer-max (T13): only rescale when the max moved by > 8 (log2 units)
    bool need = !__all((mt[0] - mrun[0] <= 8.f) && (mt[1] - mrun[1] <= 8.f));
    if (need) {
#pragma unroll
      for (int cf = 0; cf < 2; cf++) {
        float mnew = fmaxf(mrun[cf], mt[cf]);
        float al = __builtin_amdgcn_exp2f(mrun[cf] - mnew);
        mrun[cf] = mnew;
        lrun[cf] *= al;
#pragma unroll
        for (int rf = 0; rf < 4; rf++)
#pragma unroll
          for (int r = 0; r < 4; r++) ot[rf][cf][r] *= al;
      }
    }

    // P = exp2(S - m), row sums
    float ls[2] = {0.f, 0.f};
#pragma unroll
    for (int rf = 0; rf < 4; rf++)
#pragma unroll
      for (int cf = 0; cf < 2; cf++)
#pragma unroll
        for (int r = 0; r < 4; r++) {
          float p = __builtin_amdgcn_exp2f(sc[rf][cf][r] - mrun[cf]);
          sc[rf][cf][r] = p;
          ls[cf] += p;
        }
#pragma unroll
    for (int cf = 0; cf < 2; cf++) {
      float s2 = ls[cf];
      s2 += __shfl_xor(s2, 16);
      s2 += __shfl_xor(s2, 32);
      lrun[cf] += s2;
    }

    // pack P -> wave-private LDS [q][kv]
#pragma unroll
    for (int rf = 0; rf < 4; rf++)
#pragma unroll
      for (int cf = 0; cf < 2; cf++) {
        h4 p4;
#pragma unroll
        for (int r = 0; r < 4; r++) p4[r] = (_Float16)sc[rf][cf][r];
        *(h4*)&lP[w][(lq + 16 * cf) * 72 + rf * 16 + hi * 4] = p4;
      }
    asm volatile("s_waitcnt lgkmcnt(0)" ::: "memory");
    __builtin_amdgcn_sched_barrier(0);

    // O^T += V^T P^T (contraction over kv). V from shared swizzled LDS.
    {
      const _Float16* vb = &lV[tk & 1][0];
#pragma unroll
      for (int kvc = 0; kvc < 2; kvc++) {
        h8 vf[4];
#pragma unroll
        for (int rf = 0; rf < 4; rf++)
          vf[rf] = *(const h8*)&vb[(rf * 16 + lq) * 64 + (((kvc * 4 + hi) ^ (lq & 7)) * 8)];
        h8 pb[2];
#pragma unroll
        for (int cf = 0; cf < 2; cf++)
          pb[cf] = *(const h8*)&lP[w][(lq + 16 * cf) * 72 + kvc * 32 + hi * 8];
#pragma unroll
        for (int rf = 0; rf < 4; rf++)
#pragma unroll
          for (int cf = 0; cf < 2; cf++)
            ot[rf][cf] = __builtin_amdgcn_mfma_f32_16x16x32_f16(vf[rf], pb[cf], ot[rf][cf], 0, 0, 0);
      }
    }
    // no end-of-tile barrier: ds_read data already consumed by MFMAs above;
    // next loop-top vmcnt(0)+s_barrier orders buffer reuse.
  }

  // normalize + store to AO[b*S+q][h*64+dv] f16 (input of out-proj GEMM)
#pragma unroll
  for (int cf = 0; cf < 2; cf++) {
    float inv = 1.0f / lrun[cf];
    size_t row = (size_t)b * S_LEN + q0 + lq + 16 * cf;
#pragma unroll
    for (int rf = 0; rf < 4; rf++) {
      h4 o;
#pragma unroll
      for (int r = 0; r < 4; r++) o[r] = (_Float16)(ot[rf][cf][r] * inv);
      *(h4*)&AO[row * DMODEL + h * DH + rf * 16 + hi * 4] = o;
    }
  }
}

extern "C" void kernel_launch(void* const* d_in, const int* in_sizes, int n_in,
                              void* d_out, int out_size, void* d_ws, size_t ws_size,
                              hipStream_t stream) {
  const float* x  = (const float*)d_in[0];
  const float* Wq = (const float*)d_in[1];
  const float* Wk = (const float*)d_in[2];
  const float* Wv = (const float*)d_in[3];
  const float* Wo = (const float*)d_in[4];
  const float* tp = (const float*)d_in[5];

  float* y  = (float*)d_out;                 // 16,777,216 f32
  float* Ko = y + (size_t)16777216;          //  4,194,304 (post-RoPE K fp32)
  float* Vo = Ko + (size_t)4194304;          //  4,194,304 (V fp32)

  // workspace carve (fp16 elems) — total 68.5 MB. xh..woh adjacent => single cvt;
  // wqh/wkh/wvh adjacent => ONE fused QKV GEMM (N=3072; 2048/2560 are 128-aligned).
  _Float16* xh  = (_Float16*)d_ws;           // 16,777,216
  _Float16* wqh = xh + 16777216;             //  4,194,304
  _Float16* wkh = wqh + 4194304;             //  1,048,576
  _Float16* wvh = wkh + 1048576;             //  1,048,576
  _Float16* woh = wvh + 1048576;             //  4,194,304
  _Float16* Kh  = woh + 4194304;             //  4,194,304  [b][g][s][64]
  _Float16* Vth = Kh + 4194304;              //  4,194,304  [b][g][64][s]
  float2*   rtab = (float2*)(Vth + 4194304); //    524,288 B
  _Float16* AOh = xh;                        // alias: x dead after QKV GEMM
  _Float16* Qh  = (_Float16*)d_out;          // alias: first 32MB of y; y written last
  (void)wkh; (void)wvh;

  cvt_all<<<2048, 256, 0, stream>>>(x, Wq, Wk, Wv, Wo, xh);
  rope_table_k<<<256, 256, 0, stream>>>(rtab);

  gemm128<1><<<dim3(24, 64), 512, 0, stream>>>(xh, wqh, Qh, Kh, Ko, Vth, Vo, nullptr, rtab, tp);
  attn_fwd<<<dim3(8, 256), 256, 0, stream>>>(Qh, Kh, Vth, AOh);
  gemm128<3><<<dim3(16, 64), 512, 0, stream>>>(AOh, woh, nullptr, nullptr, nullptr, nullptr, nullptr, y, rtab, tp);
}